// Round 17
// baseline (202.920 us; speedup 1.0000x reference)
//
#include <hip/hip_runtime.h>
#include <hip/hip_bf16.h>

#define N_NODES 50000
#define N_EDGES 1600000
#define DIM 128
#define N_LAYERS 3
#define N_GRAPHS 128

#define NBUCK 196          // buckets of 256 nodes
#define CAP   12288        // per-bucket PADDED edge capacity (mean ~10240)
#define T1    4096         // edges per partition block
#define G1    ((N_EDGES + T1 - 1) / T1)   // 391
#define ZROW  50000        // zero-row sentinel index (fp8 row of zeros)

#define CVT_BLKS 6250      // 1.6M float4 / 256
#define PACK_BLKS 48       // 12288 pack threads / 256

typedef __attribute__((ext_vector_type(8))) short bf16x8;
typedef __attribute__((ext_vector_type(4))) float f32x4;
typedef __attribute__((ext_vector_type(2))) float f32x2;
typedef __attribute__((ext_vector_type(4))) int i32x4;
typedef __attribute__((ext_vector_type(2))) unsigned int u32x2;

// ------------------------------------------------------------ bf16 helpers
__device__ __forceinline__ unsigned short f2bfu(float f) {
    __hip_bfloat16 h = __float2bfloat16(f);  // RNE
    return *reinterpret_cast<unsigned short*>(&h);
}
__device__ __forceinline__ void acc8(i32x4 v, float* a) {
    union { int i; float f; } t;
    t.i = v.x << 16;         a[0] += t.f;
    t.i = v.x & 0xffff0000;  a[1] += t.f;
    t.i = v.y << 16;         a[2] += t.f;
    t.i = v.y & 0xffff0000;  a[3] += t.f;
    t.i = v.z << 16;         a[4] += t.f;
    t.i = v.z & 0xffff0000;  a[5] += t.f;
    t.i = v.w << 16;         a[6] += t.f;
    t.i = v.w & 0xffff0000;  a[7] += t.f;
}
// unpack 8 fp8 (e4m3) from 8B and accumulate
__device__ __forceinline__ void accf8(u32x2 w, float* a) {
    f32x2 p0 = __builtin_amdgcn_cvt_pk_f32_fp8((int)w.x, false);
    f32x2 p1 = __builtin_amdgcn_cvt_pk_f32_fp8((int)w.x, true);
    f32x2 p2 = __builtin_amdgcn_cvt_pk_f32_fp8((int)w.y, false);
    f32x2 p3 = __builtin_amdgcn_cvt_pk_f32_fp8((int)w.y, true);
    a[0] += p0.x; a[1] += p0.y; a[2] += p1.x; a[3] += p1.y;
    a[4] += p2.x; a[5] += p2.y; a[6] += p3.x; a[7] += p3.y;
}
__device__ __forceinline__ unsigned char f2fp8(float v) {
    return (unsigned char)(__builtin_amdgcn_cvt_pk_fp8_f32(v, v, 0, false) & 0xFF);
}

// --------------------- prep: cvt x->bf16 + x->fp8 + pack W + cursors + zero-rows
__global__ __launch_bounds__(256) void prep_kernel(const float4* __restrict__ x4,
                                                   const float* __restrict__ Wl,
                                                   const float* __restrict__ Wr,
                                                   ushort4* __restrict__ xb4,
                                                   unsigned int* __restrict__ xf8uA,
                                                   unsigned int* __restrict__ xf8uB,
                                                   unsigned short* __restrict__ wp,
                                                   int* __restrict__ cursor) {
    int bid = blockIdx.x;
    if (bid < CVT_BLKS) {
        int i = bid * 256 + threadIdx.x;   // < 1.6M float4s
        float4 v = x4[i];
        ushort4 o;
        o.x = f2bfu(v.x); o.y = f2bfu(v.y); o.z = f2bfu(v.z); o.w = f2bfu(v.w);
        xb4[i] = o;
        int w = __builtin_amdgcn_cvt_pk_fp8_f32(v.x, v.y, 0, false);
        w = __builtin_amdgcn_cvt_pk_fp8_f32(v.z, v.w, w, true);
        xf8uA[i] = (unsigned int)w;
        return;
    }
    if (bid < CVT_BLKS + PACK_BLKS) {
        int t = (bid - CVT_BLKS) * 256 + threadIdx.x;
        if (t >= 3 * 2 * 4 * 8 * 64) return;
        int lane = t & 63;
        int rest = t >> 6;
        int ct = rest & 7; rest >>= 3;
        int kt = rest & 3; rest >>= 2;
        int mat = rest & 1; rest >>= 1;
        int layer = rest;
        const float* W = (mat ? Wr : Wl) + (size_t)layer * DIM * DIM;
        int col = ct * 16 + (lane & 15);
        int k0 = kt * 32 + (lane >> 4) * 8;
        unsigned short* dst = wp + (size_t)t * 8;
#pragma unroll
        for (int j = 0; j < 8; j++) dst[j] = f2bfu(W[(k0 + j) * DIM + col]);
        return;
    }
    // cursor init + zero-rows in BOTH fp8 buffers
    if (threadIdx.x < NBUCK) cursor[threadIdx.x] = threadIdx.x * CAP;
    if (threadIdx.x < 32) {
        xf8uA[(size_t)ZROW * 32 + threadIdx.x] = 0u;
        xf8uB[(size_t)ZROW * 32 + threadIdx.x] = 0u;
    }
}

// ------------------------------------------- CSR build (2 passes, fixed caps)
__global__ __launch_bounds__(256) void pass1_partition(const int* __restrict__ ei,
                                                       int* __restrict__ cursor,
                                                       unsigned int* __restrict__ pairs) {
    __shared__ int h[256], sc[256], o[256], c[256], gb[256];
    __shared__ unsigned int stg[T1];
    int tid = threadIdx.x;
    int e0 = blockIdx.x * T1;
    int e1 = min(e0 + T1, N_EDGES);
    h[tid] = 0;
    __syncthreads();
    for (int e = e0 + tid; e < e1; e += 256) atomicAdd(&h[ei[N_EDGES + e] >> 8], 1);
    __syncthreads();
    int myc = h[tid];
    sc[tid] = myc;
    __syncthreads();
    for (int off = 1; off < 256; off <<= 1) {
        int t = (tid >= off) ? sc[tid - off] : 0;
        __syncthreads();
        sc[tid] += t;
        __syncthreads();
    }
    o[tid] = sc[tid] - myc;
    c[tid] = o[tid];
    __syncthreads();
    for (int e = e0 + tid; e < e1; e += 256) {
        unsigned int s = (unsigned int)ei[e];
        unsigned int d = (unsigned int)ei[N_EDGES + e];
        int p = atomicAdd(&c[d >> 8], 1);
        stg[p] = (d << 16) | s;
    }
    __syncthreads();
    if (tid < NBUCK && myc) gb[tid] = atomicAdd(&cursor[tid], myc);
    __syncthreads();
    int cnt = e1 - e0;
    for (int j = tid; j < cnt; j += 256) {
        unsigned int v = stg[j];
        int bk = v >> 24;           // dst>>8
        pairs[gb[bk] + (j - o[bk])] = v;
    }
}

// pass2: one block per bucket. PAIR-PADDED layout (round 13, verified).
__global__ __launch_bounds__(256) void pass2_fill(const unsigned int* __restrict__ pairs,
                                                  const int* __restrict__ cursor,
                                                  unsigned int* __restrict__ rp,
                                                  float* __restrict__ inv_deg,
                                                  unsigned short* __restrict__ csr16) {
    __shared__ int lh[256], sc[256], lf[256];
    int tid = threadIdx.x;
    int b = blockIdx.x;
    int p0 = b * CAP, p1 = cursor[b];
    lh[tid] = 0;
    __syncthreads();
    for (int p = p0 + tid; p < p1; p += 256) atomicAdd(&lh[(pairs[p] >> 16) & 255], 1);
    __syncthreads();
    int deg = lh[tid];
    int pdeg = max(deg, lh[tid ^ 1]);        // pair max
    int padL = (pdeg + 7) & ~7;              // round to 8
    sc[tid] = padL;
    __syncthreads();
    for (int off = 1; off < 256; off <<= 1) {
        int t = (tid >= off) ? sc[tid - off] : 0;
        __syncthreads();
        sc[tid] += t;
        __syncthreads();
    }
    int base = p0 + sc[tid] - padL;
    int node = (b << 8) + tid;
    if (node < N_NODES) {
        rp[node] = (unsigned int)base | ((unsigned int)deg << 24);
        inv_deg[node] = (deg > 0) ? 1.0f / (float)deg : 0.0f;
    }
    lf[tid] = base;
    __syncthreads();
    for (int k = deg; k < padL; k++) csr16[base + k] = (unsigned short)ZROW;
    for (int p = p0 + tid; p < p1; p += 256) {
        unsigned int v = pairs[p];
        int pos = atomicAdd(&lf[(v >> 16) & 255], 1);
        csr16[pos] = (unsigned short)(v & 0xFFFF);
    }
}

// ------------------------------------------------------- fused agg + GEMM
// Block = 512 threads = 8 waves = 16 output rows (one GEMM row-tile).
// Phase 1 (gather): wave wv runs the round-14 pair-gather for pair R0/2+wv,
//   writing the mean rows into LDS (padded [16][136] -> conflict-light).
// Phase 2 (gemm): wave wv owns col-tile wv; A agg-side from LDS, x-side
//   streamed from xb; epilogue writes bf16 (+fused fp8 for next layer).
template <int RELU, int WRITE_FP8>
__global__ __launch_bounds__(512) void fused_layer_kernel(
    const unsigned char* __restrict__ xf8_in,
    const unsigned short* __restrict__ xb,
    const unsigned short* __restrict__ csr16,
    const unsigned int* __restrict__ rp,
    const float* __restrict__ inv_deg,
    const unsigned short* __restrict__ wp,
    const float* __restrict__ bias,
    unsigned short* __restrict__ outb,
    unsigned char* __restrict__ outf8) {
    __shared__ unsigned short sAgg[16][DIM + 8];
    const int R0 = blockIdx.x * 16;
    const int wv = threadIdx.x >> 6;     // 0..7
    const int lane = threadIdx.x & 63;

    // ---------------- phase 1: gather (round-14 inner loop, bit-identical)
    {
        const int na   = lane >> 5;          // node within pair
        const int slot = (lane >> 4) & 1;    // edge-quad slot within node
        const int sub  = lane & 15;          // 8B piece of 128B fp8 row
        int n0 = R0 + wv * 2;
        unsigned int r0 = rp[n0], r1 = rp[n0 + 1];
        int s0 = r0 & 0xFFFFFF, s1 = r1 & 0xFFFFFF;
        int padL = s1 - s0;
        int myStart = na ? s1 : s0;
        float a[8] = {0.f, 0.f, 0.f, 0.f, 0.f, 0.f, 0.f, 0.f};
        int e = myStart + slot * 4;
        for (int it = 0; it < padL; it += 8) {
            ushort4 idx = *(const ushort4*)(csr16 + e);
            u32x2 v0 = *(const u32x2*)(xf8_in + (size_t)idx.x * DIM + sub * 8);
            u32x2 v1 = *(const u32x2*)(xf8_in + (size_t)idx.y * DIM + sub * 8);
            u32x2 v2 = *(const u32x2*)(xf8_in + (size_t)idx.z * DIM + sub * 8);
            u32x2 v3 = *(const u32x2*)(xf8_in + (size_t)idx.w * DIM + sub * 8);
            accf8(v0, a); accf8(v1, a); accf8(v2, a); accf8(v3, a);
            e += 8;
        }
#pragma unroll
        for (int k = 0; k < 8; k++) a[k] += __shfl_xor(a[k], 16);
        if (slot == 0) {
            float w = inv_deg[n0 + na];
            i32x4 o;
            o.x = ((int)f2bfu(a[1] * w) << 16) | f2bfu(a[0] * w);
            o.y = ((int)f2bfu(a[3] * w) << 16) | f2bfu(a[2] * w);
            o.z = ((int)f2bfu(a[5] * w) << 16) | f2bfu(a[4] * w);
            o.w = ((int)f2bfu(a[7] * w) << 16) | f2bfu(a[6] * w);
            *(i32x4*)(&sAgg[wv * 2 + na][sub * 8]) = o;
        }
    }
    __syncthreads();

    // ---------------- phase 2: gemm (col-tile wv)
    const int l15 = lane & 15, l4 = lane >> 4;
    float bv = bias[wv * 16 + l15];
    f32x4 acc = (f32x4){bv, bv, bv, bv};

    // mat 0: agg side, A from LDS
#pragma unroll
    for (int kt = 0; kt < 4; kt++) {
        bf16x8 a0 = *(const bf16x8*)(&sAgg[l15][kt * 32 + l4 * 8]);
        bf16x8 bf = *(const bf16x8*)(wp + kt * (8 * 64 * 8) + wv * (64 * 8) + lane * 8);
        acc = __builtin_amdgcn_mfma_f32_16x16x32_bf16(a0, bf, acc, 0, 0, 0);
    }
    // mat 1: x side, A streamed from global
    const unsigned short* wbase = wp + (4 * 8 * 64 * 8);
#pragma unroll
    for (int kt = 0; kt < 4; kt++) {
        bf16x8 a0 = *(const bf16x8*)(xb + (size_t)(R0 + l15) * DIM + kt * 32 + l4 * 8);
        bf16x8 bf = *(const bf16x8*)(wbase + kt * (8 * 64 * 8) + wv * (64 * 8) + lane * 8);
        acc = __builtin_amdgcn_mfma_f32_16x16x32_bf16(a0, bf, acc, 0, 0, 0);
    }

    int r0w = R0 + l4 * 4;
    int col = wv * 16 + l15;
#pragma unroll
    for (int j = 0; j < 4; j++) {
        float v = acc[j];
        if (RELU) v = fmaxf(v, 0.f);
        outb[(size_t)(r0w + j) * DIM + col] = f2bfu(v);
        if (WRITE_FP8) outf8[(size_t)(r0w + j) * DIM + col] = f2fp8(v);
    }
}

// ------------------------------------------------------------------- pool
__global__ __launch_bounds__(1024) void pool_kernel(const unsigned short* __restrict__ xb,
                                                    const int* __restrict__ batch,
                                                    float* __restrict__ out) {
    __shared__ float red[16][DIM];
    int g = blockIdx.x;
    int tid = threadIdx.x;
    int wv = tid >> 6;
    int lane = tid & 63;
    int fo = lane & 15;        // feature octet
    int rs = lane >> 4;        // 0..3
    int lo = 0, hi = N_NODES;
    while (lo < hi) { int m = (lo + hi) >> 1; if (batch[m] < g) lo = m + 1; else hi = m; }
    int start = lo;
    lo = 0; hi = N_NODES;
    while (lo < hi) { int m = (lo + hi) >> 1; if (batch[m] < g + 1) lo = m + 1; else hi = m; }
    int end = lo;
    float a[8] = {0.f, 0.f, 0.f, 0.f, 0.f, 0.f, 0.f, 0.f};
    for (int r = start + wv * 4 + rs; r < end; r += 64) {
        i32x4 v = *(const i32x4*)(xb + (size_t)r * DIM + fo * 8);
        acc8(v, a);
    }
#pragma unroll
    for (int k = 0; k < 8; k++) {
        a[k] += __shfl_xor(a[k], 16);
        a[k] += __shfl_xor(a[k], 32);
    }
    if (rs == 0) {
#pragma unroll
        for (int k = 0; k < 8; k++) red[wv][fo * 8 + k] = a[k];
    }
    __syncthreads();
    if (tid < DIM) {
        float s = 0.f;
#pragma unroll
        for (int w = 0; w < 16; w++) s += red[w][tid];
        out[g * DIM + tid] = s;
    }
}

// ---------------------------------------------------------------- launcher
extern "C" void kernel_launch(void* const* d_in, const int* in_sizes, int n_in,
                              void* d_out, int out_size, void* d_ws, size_t ws_size,
                              hipStream_t stream) {
    const float* x   = (const float*)d_in[0];
    const int*   ei  = (const int*)d_in[1];
    const int*   bat = (const int*)d_in[2];
    const float* Wl  = (const float*)d_in[3];
    const float* Wr  = (const float*)d_in[4];
    const float* b   = (const float*)d_in[5];
    float* out = (float*)d_out;

    char* ws = (char*)d_ws;
    size_t off = 0;
    auto carve = [&](size_t bytes) {
        void* p = ws + off;
        off += (bytes + 255) & ~(size_t)255;
        return p;
    };
    int*            cursor  = (int*)carve(sizeof(int) * 256);
    unsigned int*   rp      = (unsigned int*)carve(sizeof(unsigned int) * N_NODES);
    unsigned short* csr16   = (unsigned short*)carve(sizeof(unsigned short) * NBUCK * CAP);
    float*          inv_deg = (float*)carve(sizeof(float) * N_NODES);
    unsigned char*  xf8A    = (unsigned char*)carve(1ull * (N_NODES + 1) * DIM);  // +zero row
    unsigned char*  xf8B    = (unsigned char*)carve(1ull * (N_NODES + 1) * DIM);  // +zero row
    unsigned short* xb      = (unsigned short*)carve(2ull * N_NODES * DIM);
    unsigned short* actA    = (unsigned short*)carve(2ull * N_NODES * DIM);
    unsigned short* actB    = (unsigned short*)carve(2ull * N_NODES * DIM);
    unsigned short* wpack   = (unsigned short*)carve(2ull * 3 * 2 * 4 * 8 * 64 * 8);
    // pairs (6.4MB) aliases actB: dead before layer-1 fused kernel writes actB
    unsigned int*   pairs  = (unsigned int*)actB;
    unsigned short* finalb = actA;   // layer-2 output (actA dead by then)
    (void)ws_size; (void)in_sizes; (void)n_in; (void)out_size;

    prep_kernel<<<CVT_BLKS + PACK_BLKS + 1, 256, 0, stream>>>(
        (const float4*)x, Wl, Wr, (ushort4*)xb,
        (unsigned int*)xf8A, (unsigned int*)xf8B, wpack, cursor);
    pass1_partition<<<G1, 256, 0, stream>>>(ei, cursor, pairs);
    pass2_fill<<<NBUCK, 256, 0, stream>>>(pairs, cursor, rp, inv_deg, csr16);

    const int fusedGrid = N_NODES / 16;   // 3125 blocks x 512 threads
    const size_t wlayer = 2ull * 4 * 8 * 64 * 8;

    // layer 0: gather from xf8A, x-side xb; write actA + xf8B
    fused_layer_kernel<1, 1><<<fusedGrid, 512, 0, stream>>>(
        xf8A, xb, csr16, rp, inv_deg, wpack + 0 * wlayer, b + 0 * DIM, actA, xf8B);
    // layer 1: gather from xf8B, x-side actA; write actB + xf8A
    fused_layer_kernel<1, 1><<<fusedGrid, 512, 0, stream>>>(
        xf8B, actA, csr16, rp, inv_deg, wpack + 1 * wlayer, b + 1 * DIM, actB, xf8A);
    // layer 2: gather from xf8A, x-side actB; write finalb (no relu, no fp8)
    fused_layer_kernel<0, 0><<<fusedGrid, 512, 0, stream>>>(
        xf8A, actB, csr16, rp, inv_deg, wpack + 2 * wlayer, b + 2 * DIM, finalb, nullptr);

    pool_kernel<<<N_GRAPHS, 1024, 0, stream>>>(finalb, bat, out);
}

// Round 18
// 185.013 us; speedup vs baseline: 1.0968x; 1.0968x over previous
//
#include <hip/hip_runtime.h>
#include <hip/hip_bf16.h>

#define N_NODES 50000
#define N_EDGES 1600000
#define DIM 128
#define N_LAYERS 3
#define N_GRAPHS 128

#define NBUCK 196          // buckets of 256 nodes
#define CAP   12288        // per-bucket PADDED edge capacity (mean ~10240)
#define T1    4096         // edges per partition block
#define G1    ((N_EDGES + T1 - 1) / T1)   // 391
#define ZROW  50000        // zero-row sentinel index (fp8 row of zeros)

#define CVT_BLKS 6250      // 1.6M float4 / 256
#define PACK_BLKS 48       // 12288 pack threads / 256

typedef __attribute__((ext_vector_type(8))) short bf16x8;
typedef __attribute__((ext_vector_type(4))) float f32x4;
typedef __attribute__((ext_vector_type(2))) float f32x2;
typedef __attribute__((ext_vector_type(4))) int i32x4;
typedef __attribute__((ext_vector_type(2))) unsigned int u32x2;

// ------------------------------------------------------------ bf16 helpers
__device__ __forceinline__ unsigned short f2bfu(float f) {
    __hip_bfloat16 h = __float2bfloat16(f);  // RNE
    return *reinterpret_cast<unsigned short*>(&h);
}
__device__ __forceinline__ void acc8(i32x4 v, float* a) {
    union { int i; float f; } t;
    t.i = v.x << 16;         a[0] += t.f;
    t.i = v.x & 0xffff0000;  a[1] += t.f;
    t.i = v.y << 16;         a[2] += t.f;
    t.i = v.y & 0xffff0000;  a[3] += t.f;
    t.i = v.z << 16;         a[4] += t.f;
    t.i = v.z & 0xffff0000;  a[5] += t.f;
    t.i = v.w << 16;         a[6] += t.f;
    t.i = v.w & 0xffff0000;  a[7] += t.f;
}
// unpack 8 fp8 (e4m3) from 8B and accumulate
__device__ __forceinline__ void accf8(u32x2 w, float* a) {
    f32x2 p0 = __builtin_amdgcn_cvt_pk_f32_fp8((int)w.x, false);
    f32x2 p1 = __builtin_amdgcn_cvt_pk_f32_fp8((int)w.x, true);
    f32x2 p2 = __builtin_amdgcn_cvt_pk_f32_fp8((int)w.y, false);
    f32x2 p3 = __builtin_amdgcn_cvt_pk_f32_fp8((int)w.y, true);
    a[0] += p0.x; a[1] += p0.y; a[2] += p1.x; a[3] += p1.y;
    a[4] += p2.x; a[5] += p2.y; a[6] += p3.x; a[7] += p3.y;
}
__device__ __forceinline__ unsigned char f2fp8(float v) {
    return (unsigned char)(__builtin_amdgcn_cvt_pk_fp8_f32(v, v, 0, false) & 0xFF);
}

// --------------------- prep: cvt x->bf16 + x->fp8 + pack W + cursors + zero-row
__global__ __launch_bounds__(256) void prep_kernel(const float4* __restrict__ x4,
                                                   const float* __restrict__ Wl,
                                                   const float* __restrict__ Wr,
                                                   ushort4* __restrict__ xb4,
                                                   unsigned int* __restrict__ xf8u,
                                                   unsigned short* __restrict__ wp,
                                                   int* __restrict__ cursor) {
    int bid = blockIdx.x;
    if (bid < CVT_BLKS) {
        int i = bid * 256 + threadIdx.x;   // < 1.6M float4s
        float4 v = x4[i];
        ushort4 o;
        o.x = f2bfu(v.x); o.y = f2bfu(v.y); o.z = f2bfu(v.z); o.w = f2bfu(v.w);
        xb4[i] = o;
        int w = __builtin_amdgcn_cvt_pk_fp8_f32(v.x, v.y, 0, false);
        w = __builtin_amdgcn_cvt_pk_fp8_f32(v.z, v.w, w, true);
        xf8u[i] = (unsigned int)w;
        return;
    }
    if (bid < CVT_BLKS + PACK_BLKS) {
        int t = (bid - CVT_BLKS) * 256 + threadIdx.x;
        if (t >= 3 * 2 * 4 * 8 * 64) return;
        int lane = t & 63;
        int rest = t >> 6;
        int ct = rest & 7; rest >>= 3;
        int kt = rest & 3; rest >>= 2;
        int mat = rest & 1; rest >>= 1;
        int layer = rest;
        const float* W = (mat ? Wr : Wl) + (size_t)layer * DIM * DIM;
        int col = ct * 16 + (lane & 15);
        int k0 = kt * 32 + (lane >> 4) * 8;
        unsigned short* dst = wp + (size_t)t * 8;
#pragma unroll
        for (int j = 0; j < 8; j++) dst[j] = f2bfu(W[(k0 + j) * DIM + col]);
        return;
    }
    // cursor init + zero-row (row ZROW of fp8 table = 32 uints)
    if (threadIdx.x < NBUCK) cursor[threadIdx.x] = threadIdx.x * CAP;
    if (threadIdx.x < 32) xf8u[(size_t)ZROW * 32 + threadIdx.x] = 0u;
}

// ------------------------------------------- CSR build (2 passes, fixed caps)
__global__ __launch_bounds__(256) void pass1_partition(const int* __restrict__ ei,
                                                       int* __restrict__ cursor,
                                                       unsigned int* __restrict__ pairs) {
    __shared__ int h[256], sc[256], o[256], c[256], gb[256];
    __shared__ unsigned int stg[T1];
    int tid = threadIdx.x;
    int e0 = blockIdx.x * T1;
    int e1 = min(e0 + T1, N_EDGES);
    h[tid] = 0;
    __syncthreads();
    for (int e = e0 + tid; e < e1; e += 256) atomicAdd(&h[ei[N_EDGES + e] >> 8], 1);
    __syncthreads();
    int myc = h[tid];
    sc[tid] = myc;
    __syncthreads();
    for (int off = 1; off < 256; off <<= 1) {
        int t = (tid >= off) ? sc[tid - off] : 0;
        __syncthreads();
        sc[tid] += t;
        __syncthreads();
    }
    o[tid] = sc[tid] - myc;
    c[tid] = o[tid];
    __syncthreads();
    for (int e = e0 + tid; e < e1; e += 256) {
        unsigned int s = (unsigned int)ei[e];
        unsigned int d = (unsigned int)ei[N_EDGES + e];
        int p = atomicAdd(&c[d >> 8], 1);
        stg[p] = (d << 16) | s;
    }
    __syncthreads();
    if (tid < NBUCK && myc) gb[tid] = atomicAdd(&cursor[tid], myc);
    __syncthreads();
    int cnt = e1 - e0;
    for (int j = tid; j < cnt; j += 256) {
        unsigned int v = stg[j];
        int bk = v >> 24;           // dst>>8
        pairs[gb[bk] + (j - o[bk])] = v;
    }
}

// pass2: one block per bucket. PAIR-PADDED layout (round 13, verified).
__global__ __launch_bounds__(256) void pass2_fill(const unsigned int* __restrict__ pairs,
                                                  const int* __restrict__ cursor,
                                                  unsigned int* __restrict__ rp,
                                                  float* __restrict__ inv_deg,
                                                  unsigned short* __restrict__ csr16) {
    __shared__ int lh[256], sc[256], lf[256];
    int tid = threadIdx.x;
    int b = blockIdx.x;
    int p0 = b * CAP, p1 = cursor[b];
    lh[tid] = 0;
    __syncthreads();
    for (int p = p0 + tid; p < p1; p += 256) atomicAdd(&lh[(pairs[p] >> 16) & 255], 1);
    __syncthreads();
    int deg = lh[tid];
    int pdeg = max(deg, lh[tid ^ 1]);        // pair max
    int padL = (pdeg + 7) & ~7;              // round to 8
    sc[tid] = padL;
    __syncthreads();
    for (int off = 1; off < 256; off <<= 1) {
        int t = (tid >= off) ? sc[tid - off] : 0;
        __syncthreads();
        sc[tid] += t;
        __syncthreads();
    }
    int base = p0 + sc[tid] - padL;
    int node = (b << 8) + tid;
    if (node < N_NODES) {
        rp[node] = (unsigned int)base | ((unsigned int)deg << 24);
        inv_deg[node] = (deg > 0) ? 1.0f / (float)deg : 0.0f;
    }
    lf[tid] = base;
    __syncthreads();
    for (int k = deg; k < padL; k++) csr16[base + k] = (unsigned short)ZROW;
    for (int p = p0 + tid; p < p1; p += 256) {
        unsigned int v = pairs[p];
        int pos = atomicAdd(&lf[(v >> 16) & 255], 1);
        csr16[pos] = (unsigned short)(v & 0xFFFF);
    }
}

// ------------------------------------------------------------- aggregation
// Round-14 pair-per-wave fp8 gather + UNROLL x2: 16 edges/node/iter, 8 row
// loads in flight (was 4). Uniform 8-edge tail (padL % 16 == 8 case) — padL
// is shared by both nodes of the pair, so no divergence.
__global__ __launch_bounds__(256) void agg_kernel(const unsigned char* __restrict__ xf8,
                                                  const unsigned short* __restrict__ csr16,
                                                  const unsigned int* __restrict__ rp,
                                                  const float* __restrict__ inv_deg,
                                                  unsigned short* __restrict__ aggb) {
    int pairi = blockIdx.x * 4 + (threadIdx.x >> 6);   // 4 waves/block
    int lane = threadIdx.x & 63;
    const int na   = lane >> 5;          // node within pair
    const int slot = (lane >> 4) & 1;    // edge-quad slot within node
    const int sub  = lane & 15;          // 8B piece of 128B fp8 row
    int n0 = pairi * 2;
    unsigned int r0 = rp[n0], r1 = rp[n0 + 1];
    int s0 = r0 & 0xFFFFFF, s1 = r1 & 0xFFFFFF;
    int padL = s1 - s0;                  // pair-common padded length
    int myStart = na ? s1 : s0;
    float a[8] = {0.f, 0.f, 0.f, 0.f, 0.f, 0.f, 0.f, 0.f};
    int e = myStart + slot * 4;
    int it = 0;
    for (; it + 16 <= padL; it += 16) {
        ushort4 ia = *(const ushort4*)(csr16 + e);       // 4 indices
        ushort4 ib = *(const ushort4*)(csr16 + e + 8);   // next 4
        u32x2 v0 = *(const u32x2*)(xf8 + (size_t)ia.x * DIM + sub * 8);
        u32x2 v1 = *(const u32x2*)(xf8 + (size_t)ia.y * DIM + sub * 8);
        u32x2 v2 = *(const u32x2*)(xf8 + (size_t)ia.z * DIM + sub * 8);
        u32x2 v3 = *(const u32x2*)(xf8 + (size_t)ia.w * DIM + sub * 8);
        u32x2 v4 = *(const u32x2*)(xf8 + (size_t)ib.x * DIM + sub * 8);
        u32x2 v5 = *(const u32x2*)(xf8 + (size_t)ib.y * DIM + sub * 8);
        u32x2 v6 = *(const u32x2*)(xf8 + (size_t)ib.z * DIM + sub * 8);
        u32x2 v7 = *(const u32x2*)(xf8 + (size_t)ib.w * DIM + sub * 8);
        accf8(v0, a); accf8(v1, a); accf8(v2, a); accf8(v3, a);
        accf8(v4, a); accf8(v5, a); accf8(v6, a); accf8(v7, a);
        e += 16;
    }
    if (it < padL) {  // uniform 8-edge tail
        ushort4 idx = *(const ushort4*)(csr16 + e);
        u32x2 v0 = *(const u32x2*)(xf8 + (size_t)idx.x * DIM + sub * 8);
        u32x2 v1 = *(const u32x2*)(xf8 + (size_t)idx.y * DIM + sub * 8);
        u32x2 v2 = *(const u32x2*)(xf8 + (size_t)idx.z * DIM + sub * 8);
        u32x2 v3 = *(const u32x2*)(xf8 + (size_t)idx.w * DIM + sub * 8);
        accf8(v0, a); accf8(v1, a); accf8(v2, a); accf8(v3, a);
    }
#pragma unroll
    for (int k = 0; k < 8; k++) a[k] += __shfl_xor(a[k], 16);  // slot combine
    if (slot == 0) {
        int node = n0 + na;
        float w = inv_deg[node];
        i32x4 o;
        o.x = ((int)f2bfu(a[1] * w) << 16) | f2bfu(a[0] * w);
        o.y = ((int)f2bfu(a[3] * w) << 16) | f2bfu(a[2] * w);
        o.z = ((int)f2bfu(a[5] * w) << 16) | f2bfu(a[4] * w);
        o.w = ((int)f2bfu(a[7] * w) << 16) | f2bfu(a[6] * w);
        *(i32x4*)(aggb + (size_t)node * DIM + sub * 8) = o;
    }
}

// ---------------------------------------------------------------- MFMA GEMM
// v3 (round 16, verified): one wave owns ONE row-tile x ALL 8 col-tiles.
// 3125 waves / 782 blocks; each A row loaded by exactly one wave.
template <int RELU, int WRITE_FP8>
__global__ __launch_bounds__(256) void gemm_mfma_kernel(
    const unsigned short* __restrict__ aggb,
    const unsigned short* __restrict__ xb,
    const unsigned short* __restrict__ wp,
    const float* __restrict__ bias,
    unsigned short* __restrict__ outb,
    unsigned char* __restrict__ outf8) {
    const int NT = N_NODES / 16;  // 3125
    int wid = (blockIdx.x * blockDim.x + threadIdx.x) >> 6;  // row-tile id
    int lane = threadIdx.x & 63;
    if (wid >= NT) return;
    const int R0 = wid * 16;
    const int l15 = lane & 15, l4 = lane >> 4;

    f32x4 acc[8];
#pragma unroll
    for (int c = 0; c < 8; c++) {
        float bv = bias[c * 16 + l15];
        acc[c] = (f32x4){bv, bv, bv, bv};
    }

#pragma unroll
    for (int mat = 0; mat < 2; mat++) {
        const unsigned short* src = mat ? xb : aggb;
        const unsigned short* wbase = wp + mat * (4 * 8 * 64 * 8);
#pragma unroll
        for (int kt = 0; kt < 4; kt++) {
            bf16x8 a0 = *(const bf16x8*)(src + (size_t)(R0 + l15) * DIM + kt * 32 + l4 * 8);
            const unsigned short* wk = wbase + kt * (8 * 64 * 8) + lane * 8;
#pragma unroll
            for (int c = 0; c < 8; c++) {
                bf16x8 bf = *(const bf16x8*)(wk + c * (64 * 8));
                acc[c] = __builtin_amdgcn_mfma_f32_16x16x32_bf16(a0, bf, acc[c], 0, 0, 0);
            }
        }
    }

    int r0 = R0 + l4 * 4;
#pragma unroll
    for (int c = 0; c < 8; c++) {
        int col = c * 16 + l15;
#pragma unroll
        for (int j = 0; j < 4; j++) {
            float v = acc[c][j];
            if (RELU) v = fmaxf(v, 0.f);
            outb[(size_t)(r0 + j) * DIM + col] = f2bfu(v);
            if (WRITE_FP8) outf8[(size_t)(r0 + j) * DIM + col] = f2fp8(v);
        }
    }
}

// ------------------------------------------------------------------- pool
__global__ __launch_bounds__(1024) void pool_kernel(const unsigned short* __restrict__ xb,
                                                    const int* __restrict__ batch,
                                                    float* __restrict__ out) {
    __shared__ float red[16][DIM];
    int g = blockIdx.x;
    int tid = threadIdx.x;
    int wv = tid >> 6;
    int lane = tid & 63;
    int fo = lane & 15;        // feature octet
    int rs = lane >> 4;        // 0..3
    int lo = 0, hi = N_NODES;
    while (lo < hi) { int m = (lo + hi) >> 1; if (batch[m] < g) lo = m + 1; else hi = m; }
    int start = lo;
    lo = 0; hi = N_NODES;
    while (lo < hi) { int m = (lo + hi) >> 1; if (batch[m] < g + 1) lo = m + 1; else hi = m; }
    int end = lo;
    float a[8] = {0.f, 0.f, 0.f, 0.f, 0.f, 0.f, 0.f, 0.f};
    for (int r = start + wv * 4 + rs; r < end; r += 64) {
        i32x4 v = *(const i32x4*)(xb + (size_t)r * DIM + fo * 8);
        acc8(v, a);
    }
#pragma unroll
    for (int k = 0; k < 8; k++) {
        a[k] += __shfl_xor(a[k], 16);
        a[k] += __shfl_xor(a[k], 32);
    }
    if (rs == 0) {
#pragma unroll
        for (int k = 0; k < 8; k++) red[wv][fo * 8 + k] = a[k];
    }
    __syncthreads();
    if (tid < DIM) {
        float s = 0.f;
#pragma unroll
        for (int w = 0; w < 16; w++) s += red[w][tid];
        out[g * DIM + tid] = s;
    }
}

// ---------------------------------------------------------------- launcher
extern "C" void kernel_launch(void* const* d_in, const int* in_sizes, int n_in,
                              void* d_out, int out_size, void* d_ws, size_t ws_size,
                              hipStream_t stream) {
    const float* x   = (const float*)d_in[0];
    const int*   ei  = (const int*)d_in[1];
    const int*   bat = (const int*)d_in[2];
    const float* Wl  = (const float*)d_in[3];
    const float* Wr  = (const float*)d_in[4];
    const float* b   = (const float*)d_in[5];
    float* out = (float*)d_out;

    char* ws = (char*)d_ws;
    size_t off = 0;
    auto carve = [&](size_t bytes) {
        void* p = ws + off;
        off += (bytes + 255) & ~(size_t)255;
        return p;
    };
    int*            cursor  = (int*)carve(sizeof(int) * 256);
    unsigned int*   rp      = (unsigned int*)carve(sizeof(unsigned int) * N_NODES);
    unsigned short* csr16   = (unsigned short*)carve(sizeof(unsigned short) * NBUCK * CAP);
    float*          inv_deg = (float*)carve(sizeof(float) * N_NODES);
    unsigned char*  xf8     = (unsigned char*)carve(1ull * (N_NODES + 1) * DIM);  // +zero row
    unsigned short* xb      = (unsigned short*)carve(2ull * N_NODES * DIM);
    unsigned short* actA    = (unsigned short*)carve(2ull * N_NODES * DIM);
    unsigned short* actB    = (unsigned short*)carve(2ull * N_NODES * DIM);
    unsigned short* aggb    = (unsigned short*)carve(2ull * N_NODES * DIM);
    unsigned short* wpack   = (unsigned short*)carve(2ull * 3 * 2 * 4 * 8 * 64 * 8);
    // aliases: pairs (6.4MB) in actB, dead before layer-1 gemm writes actB;
    // finalb (layer-2 out) in actA (dead by then).
    unsigned int*   pairs  = (unsigned int*)actB;
    unsigned short* finalb = actA;
    (void)ws_size; (void)in_sizes; (void)n_in; (void)out_size;

    prep_kernel<<<CVT_BLKS + PACK_BLKS + 1, 256, 0, stream>>>(
        (const float4*)x, Wl, Wr, (ushort4*)xb, (unsigned int*)xf8, wpack, cursor);
    pass1_partition<<<G1, 256, 0, stream>>>(ei, cursor, pairs);
    pass2_fill<<<NBUCK, 256, 0, stream>>>(pairs, cursor, rp, inv_deg, csr16);

    const int aggGrid  = N_NODES / 2 / 4;   // 25000 pair-waves, 4/block = 6250
    const int gemmGrid = (N_NODES / 16 * 64 + 255) / 256;  // 782 (3125 waves)
    const size_t wlayer = 2ull * 4 * 8 * 64 * 8;

    // layer 0 (gemm also emits fp8 act -> xf8, fused cvt8)
    agg_kernel<<<aggGrid, 256, 0, stream>>>(xf8, csr16, rp, inv_deg, aggb);
    gemm_mfma_kernel<1, 1><<<gemmGrid, 256, 0, stream>>>(aggb, xb, wpack + 0 * wlayer,
                                                         b + 0 * DIM, actA, xf8);
    // layer 1
    agg_kernel<<<aggGrid, 256, 0, stream>>>(xf8, csr16, rp, inv_deg, aggb);
    gemm_mfma_kernel<1, 1><<<gemmGrid, 256, 0, stream>>>(aggb, actA, wpack + 1 * wlayer,
                                                         b + 1 * DIM, actB, xf8);
    // layer 2 (bf16 out only, no relu)
    agg_kernel<<<aggGrid, 256, 0, stream>>>(xf8, csr16, rp, inv_deg, aggb);
    gemm_mfma_kernel<0, 0><<<gemmGrid, 256, 0, stream>>>(aggb, actB, wpack + 2 * wlayer,
                                                         b + 2 * DIM, finalb, nullptr);

    pool_kernel<<<N_GRAPHS, 1024, 0, stream>>>(finalb, bat, out);
}